// Round 3
// baseline (684.024 us; speedup 1.0000x reference)
//
#include <hip/hip_runtime.h>
#include <stdint.h>
#include <stddef.h>

#define BATCH 16
#define NROW 2048
#define CH 128
#define NLAYER 4
#define NN_TOT (BATCH * NROW)
#define EPSV 1e-5f
#define KS 64

typedef short short8 __attribute__((ext_vector_type(8)));
typedef float f32x4 __attribute__((ext_vector_type(4)));

static __device__ __forceinline__ unsigned short f2bf(float f) {
  union { float f; unsigned int i; } v;
  v.f = f;
  unsigned int u = v.i;
  return (unsigned short)((u + 0x7FFFu + ((u >> 16) & 1u)) >> 16);
}

// ---- init: Wt4[l][o][c] = bf16(W[l][c][o]) for all layers; zero stat slots --
__global__ void init_kernel(const float* __restrict__ W,
                            unsigned short* __restrict__ Wt4,
                            float* __restrict__ gsum, float* __restrict__ gsumsq) {
  const int l = blockIdx.x;   // 4 blocks
  const int t = threadIdx.x;  // 256 threads
  const float* Wl = W + (size_t)l * CH * CH;
  unsigned short* Wo = Wt4 + (size_t)l * CH * CH;
  for (int idx = t; idx < CH * CH; idx += 256) {
    int o = idx >> 7, c = idx & 127;
    Wo[idx] = f2bf(Wl[c * CH + o]);
  }
  if (l == 0) {
    for (int i = t; i < NLAYER * CH; i += 256) { gsum[i] = 0.0f; gsumsq[i] = 0.0f; }
  }
}

// ---- K1: Yt[b][o][m] = (BN_affine(X) @ W)[m][o] ----------------------------
// FIRST=1: no affine (layer 0). Otherwise s,t computed in-block from stats.
template <int FIRST>
__global__ __launch_bounds__(256) void gemm1_kernel(
    const float* __restrict__ X,             // fp32 [B*N][C]
    const unsigned short* __restrict__ Wt,   // bf16 [128][128], [o][c]
    const float* __restrict__ gp, const float* __restrict__ bp,  // gamma/beta prev
    const float* __restrict__ gsumP, const float* __restrict__ gsumsqP,
    unsigned short* __restrict__ Yt) {       // bf16 [16][128][2048]
  __shared__ unsigned short As[64 * 128];    // 16 KB, 16 swizzled 16B slots/row
  __shared__ unsigned short Bs[128 * 128];   // 32 KB
  __shared__ __align__(16) float ss[CH];
  __shared__ __align__(16) float tt[CH];
  const int tid = threadIdx.x;
  const int m0 = blockIdx.x * 64;

  if (!FIRST) {
    if (tid < CH) {
      const float inv = 1.0f / (float)NN_TOT;
      float mu = gsumP[tid] * inv;
      float var = gsumsqP[tid] * inv - mu * mu;
      float s_ = gp[tid] * rsqrtf(var + EPSV);
      ss[tid] = s_;
      tt[tid] = bp[tid] - mu * s_;
    }
    __syncthreads();
  }

#pragma unroll
  for (int j = 0; j < 4; ++j) {
    int c = tid + 256 * j;
    int r = c >> 4, slot = c & 15;
    int kc = slot ^ (r & 15);
    const float* p = X + (size_t)(m0 + r) * CH + kc * 8;
    f32x4 a = *(const f32x4*)p;
    f32x4 b = *(const f32x4*)(p + 4);
    if (!FIRST) {
      f32x4 sa = *(const f32x4*)(ss + kc * 8);
      f32x4 sb = *(const f32x4*)(ss + kc * 8 + 4);
      f32x4 ta = *(const f32x4*)(tt + kc * 8);
      f32x4 tb = *(const f32x4*)(tt + kc * 8 + 4);
      a = sa * a + ta;
      b = sb * b + tb;
    }
    short8 v;
    v[0] = (short)f2bf(a[0]); v[1] = (short)f2bf(a[1]);
    v[2] = (short)f2bf(a[2]); v[3] = (short)f2bf(a[3]);
    v[4] = (short)f2bf(b[0]); v[5] = (short)f2bf(b[1]);
    v[6] = (short)f2bf(b[2]); v[7] = (short)f2bf(b[3]);
    *(short8*)(As + c * 8) = v;
  }
#pragma unroll
  for (int j = 0; j < 8; ++j) {
    int c = tid + 256 * j;
    int r = c >> 4, slot = c & 15;
    int kc = slot ^ (r & 15);
    *(short8*)(Bs + c * 8) = *(const short8*)(Wt + (size_t)r * CH + kc * 8);
  }
  __syncthreads();

  const int l = tid & 63, w = tid >> 6;
  const int mq = (w >> 1) * 32, oq = (w & 1) * 64;
  const int lr = l & 15, lq = l >> 4;
  f32x4 acc[2][4] = {};

#pragma unroll
  for (int kt = 0; kt < 4; ++kt) {
    const int kc0 = kt * 4 + lq;
    const int slotK = kc0 ^ lr;
    short8 a[2], b[4];
#pragma unroll
    for (int mi = 0; mi < 2; ++mi)
      a[mi] = *(const short8*)(As + (mq + mi * 16 + lr) * 128 + slotK * 8);
#pragma unroll
    for (int ni = 0; ni < 4; ++ni)
      b[ni] = *(const short8*)(Bs + (oq + ni * 16 + lr) * 128 + slotK * 8);
#pragma unroll
    for (int mi = 0; mi < 2; ++mi)
#pragma unroll
      for (int ni = 0; ni < 4; ++ni)
        acc[mi][ni] = __builtin_amdgcn_mfma_f32_16x16x32_bf16(a[mi], b[ni], acc[mi][ni], 0, 0, 0);
  }

  const int bat = m0 >> 11;
  const int mb = m0 & 2047;
  unsigned short* YtB = Yt + (size_t)bat * CH * NROW;
#pragma unroll
  for (int ni = 0; ni < 4; ++ni) {
    const int o = oq + ni * 16 + lr;
    unsigned short* row = YtB + (size_t)o * NROW;
#pragma unroll
    for (int mi = 0; mi < 2; ++mi) {
      const int m = mb + mq + mi * 16 + lq * 4;
      f32x4 v = acc[mi][ni];
      unsigned short p0 = f2bf(v[0]), p1 = f2bf(v[1]);
      unsigned short p2 = f2bf(v[2]), p3 = f2bf(v[3]);
      unsigned long long packed = (unsigned long long)p0 | ((unsigned long long)p1 << 16) |
                                  ((unsigned long long)p2 << 32) | ((unsigned long long)p3 << 48);
      *(unsigned long long*)(row + m) = packed;
    }
  }
}

// ---- K2: R[b][n][c] = ReLU(adj_b @ Y_b + bias)[n][c] fp32, + channel stats -
// A (Yt) read DIRECTLY from global as MFMA fragments (L2-resident, 512KB/batch)
// with 1-slab register double-buffer. Only B (adj) goes through LDS (2x8KB
// dbuf, one raw barrier per slab, counted vmcnt). CVT=1: B from fp32 adj,
// converted in regs, bf16 copy emitted to adjO.
struct Pf {
  short8 b0, b1;              // B slab bf16 (layers 1-3)
  f32x4 f0, f1, f2, f3;       // B slab fp32 (layer 0)
};

template <int CVT>
__global__ __launch_bounds__(256) void gemm2_kernel(
    const float* __restrict__ adjF,           // fp32 [16][2048][2048] (CVT)
    const unsigned short* __restrict__ adjH,  // bf16 [16][2048][2048] (!CVT)
    unsigned short* __restrict__ adjO,        // bf16 out (CVT)
    const unsigned short* __restrict__ Yt,    // bf16 [16][128][2048]
    const float* __restrict__ bias,           // fp32 [128]
    float* __restrict__ R,                    // fp32 [32768][128]  (== d_out)
    float* __restrict__ gsumL, float* __restrict__ gsumsqL) {
  __shared__ unsigned short Bs[2][64 * KS];   // 2 x 8 KB
  __shared__ float redS[2][CH];
  __shared__ float redQ[2][CH];

  const int tid = threadIdx.x;
  const int bat = blockIdx.x >> 5;
  const int n0 = (blockIdx.x & 31) * 64;
  const unsigned short* YtB = Yt + (size_t)bat * CH * NROW;

  // B staging: slot s8 = tid&7 (8 x 16B per 64-elem row), row r8 = tid>>3.
  const int s8 = tid & 7;
  const int r8 = tid >> 3;
  const int swz8 = (s8 ^ (r8 & 7)) * 8;
  const size_t bO0 = (size_t)bat * NROW * NROW + (size_t)(n0 + r8) * NROW + s8 * 8;
  const size_t bO1 = bO0 + (size_t)32 * NROW;
  const int lB0 = r8 * KS + swz8;
  const int lB1 = lB0 + 32 * KS;

  const int l = tid & 63, w = tid >> 6;
  const int cq = (w >> 1) * 64;   // channel quadrant (A rows / D rows)
  const int nh = (w & 1) * 32;    // n half (B rows / D cols)
  const int lr = l & 15, lq = l >> 4;
  const int rsw = lr & 7;

  // direct A-fragment base: row = cq + mi*16 + lr, k = kt*64 + ks*32 + lq*8
  const unsigned short* aBase = YtB + (size_t)(cq + lr) * NROW + lq * 8;

  f32x4 acc[4][2] = {};           // [c-tile][n-tile]

  auto LOADB = [&](Pf& p, int kt) {
    const int k0 = kt * KS;
    if constexpr (CVT) {
      const float* q0 = adjF + bO0 + k0;
      const float* q1 = adjF + bO1 + k0;
      p.f0 = *(const f32x4*)q0; p.f1 = *(const f32x4*)(q0 + 4);
      p.f2 = *(const f32x4*)q1; p.f3 = *(const f32x4*)(q1 + 4);
    } else {
      p.b0 = *(const short8*)(adjH + bO0 + k0);
      p.b1 = *(const short8*)(adjH + bO1 + k0);
    }
  };

  auto WRITEB = [&](Pf& p, int buf, int kt) {
    unsigned short* Bp = Bs[buf];
    if constexpr (CVT) {
      short8 q0, q1;
      q0[0] = (short)f2bf(p.f0[0]); q0[1] = (short)f2bf(p.f0[1]);
      q0[2] = (short)f2bf(p.f0[2]); q0[3] = (short)f2bf(p.f0[3]);
      q0[4] = (short)f2bf(p.f1[0]); q0[5] = (short)f2bf(p.f1[1]);
      q0[6] = (short)f2bf(p.f1[2]); q0[7] = (short)f2bf(p.f1[3]);
      q1[0] = (short)f2bf(p.f2[0]); q1[1] = (short)f2bf(p.f2[1]);
      q1[2] = (short)f2bf(p.f2[2]); q1[3] = (short)f2bf(p.f2[3]);
      q1[4] = (short)f2bf(p.f3[0]); q1[5] = (short)f2bf(p.f3[1]);
      q1[6] = (short)f2bf(p.f3[2]); q1[7] = (short)f2bf(p.f3[3]);
      *(short8*)(Bp + lB0) = q0;
      *(short8*)(Bp + lB1) = q1;
      const int k0 = kt * KS;
      *(short8*)(adjO + bO0 + k0) = q0;
      *(short8*)(adjO + bO1 + k0) = q1;
    } else {
      *(short8*)(Bp + lB0) = p.b0;
      *(short8*)(Bp + lB1) = p.b1;
    }
  };

  auto LOADA = [&](short8* ar, int kt) {
    const int k0 = kt * KS;
#pragma unroll
    for (int mi = 0; mi < 4; ++mi)
#pragma unroll
      for (int ks = 0; ks < 2; ++ks)
        ar[mi * 2 + ks] = *(const short8*)(aBase + (size_t)mi * 16 * NROW + k0 + ks * 32);
  };

  auto COMPUTE = [&](int buf, const short8* ar) {
    const unsigned short* Bp = Bs[buf];
#pragma unroll
    for (int ks = 0; ks < 2; ++ks) {
      const int sl = ((ks * 4 + lq) ^ rsw) * 8;
      short8 b0 = *(const short8*)(Bp + (nh + 0 + lr) * KS + sl);
      short8 b1 = *(const short8*)(Bp + (nh + 16 + lr) * KS + sl);
#pragma unroll
      for (int mi = 0; mi < 4; ++mi) {
        acc[mi][0] = __builtin_amdgcn_mfma_f32_16x16x32_bf16(ar[mi * 2 + ks], b0, acc[mi][0], 0, 0, 0);
        acc[mi][1] = __builtin_amdgcn_mfma_f32_16x16x32_bf16(ar[mi * 2 + ks], b1, acc[mi][1], 0, 0, 0);
      }
    }
  };

#define BAR() do { asm volatile("s_waitcnt lgkmcnt(0)"); __builtin_amdgcn_s_barrier(); } while (0)

  Pf s0, s1;
  short8 arX[8], arY[8];
  // prologue: slab 0 -> buf0; s0 = B slab 1, s1 = B slab 2; arX = A slab 0
  LOADB(s0, 0);
  LOADA(arX, 0);
  WRITEB(s0, 0, 0);       // counted vmcnt wait (arX loads stay in flight)
  LOADB(s0, 1);
  LOADB(s1, 2);
  BAR();

  // invariant at phase kt: buf[kt&1]=B slab kt, arX/arY alternate A slabs
#pragma unroll 1
  for (int kt2 = 0; kt2 < 14; ++kt2) {
    const int kt = kt2 * 2;
    LOADA(arY, kt + 1);
    WRITEB(s0, 1, kt + 1);
    LOADB(s0, kt + 3);
    COMPUTE(0, arX);        // slab kt
    BAR();
    LOADA(arX, kt + 2);
    WRITEB(s1, 0, kt + 2);
    LOADB(s1, kt + 4);
    COMPUTE(1, arY);        // slab kt+1
    BAR();
  }
  // tail: slabs 28..31 (arX = 28, s0 = B29, s1 = B30 on entry)
  LOADA(arY, 29);
  WRITEB(s0, 1, 29);
  LOADB(s0, 31);
  COMPUTE(0, arX);          // 28
  BAR();
  LOADA(arX, 30);
  WRITEB(s1, 0, 30);
  COMPUTE(1, arY);          // 29
  BAR();
  LOADA(arY, 31);
  WRITEB(s0, 1, 31);
  COMPUTE(0, arX);          // 30
  BAR();
  COMPUTE(1, arY);          // 31
#undef BAR

  // epilogue: bias + relu + fp32 store + channel stats
  float* RB = R + (size_t)bat * NROW * CH;
  f32x4 sumv[4] = {};
  f32x4 sumq[4] = {};
#pragma unroll
  for (int mi = 0; mi < 4; ++mi) {
    const int c0 = cq + mi * 16 + lq * 4;
    f32x4 bia = *(const f32x4*)(bias + c0);
#pragma unroll
    for (int ni = 0; ni < 2; ++ni) {
      const int n = n0 + nh + ni * 16 + lr;
      f32x4 v = acc[mi][ni] + bia;
      v[0] = fmaxf(v[0], 0.0f);
      v[1] = fmaxf(v[1], 0.0f);
      v[2] = fmaxf(v[2], 0.0f);
      v[3] = fmaxf(v[3], 0.0f);
      sumv[mi] += v;
      sumq[mi] += v * v;
      *(f32x4*)(RB + (size_t)n * CH + c0) = v;
    }
  }
#pragma unroll
  for (int mi = 0; mi < 4; ++mi) {
#pragma unroll
    for (int d = 1; d < 16; d <<= 1) {
      sumv[mi][0] += __shfl_xor(sumv[mi][0], d);
      sumv[mi][1] += __shfl_xor(sumv[mi][1], d);
      sumv[mi][2] += __shfl_xor(sumv[mi][2], d);
      sumv[mi][3] += __shfl_xor(sumv[mi][3], d);
      sumq[mi][0] += __shfl_xor(sumq[mi][0], d);
      sumq[mi][1] += __shfl_xor(sumq[mi][1], d);
      sumq[mi][2] += __shfl_xor(sumq[mi][2], d);
      sumq[mi][3] += __shfl_xor(sumq[mi][3], d);
    }
  }
  const int nqi = w & 1;
  if (lr == 0) {
#pragma unroll
    for (int mi = 0; mi < 4; ++mi) {
      const int c0 = cq + mi * 16 + lq * 4;
      redS[nqi][c0 + 0] = sumv[mi][0];
      redS[nqi][c0 + 1] = sumv[mi][1];
      redS[nqi][c0 + 2] = sumv[mi][2];
      redS[nqi][c0 + 3] = sumv[mi][3];
      redQ[nqi][c0 + 0] = sumq[mi][0];
      redQ[nqi][c0 + 1] = sumq[mi][1];
      redQ[nqi][c0 + 2] = sumq[mi][2];
      redQ[nqi][c0 + 3] = sumq[mi][3];
    }
  }
  __syncthreads();
  if (tid < CH) {
    atomicAdd(gsumL + tid, redS[0][tid] + redS[1][tid]);
  } else {
    const int c = tid - CH;
    atomicAdd(gsumsqL + c, redQ[0][c] + redQ[1][c]);
  }
}

// ---- final BN applied in place on d_out (fp32), s/t computed in-block ------
__global__ __launch_bounds__(256) void out_kernel(
    float* __restrict__ out,
    const float* __restrict__ g3, const float* __restrict__ b3,
    const float* __restrict__ gsum3, const float* __restrict__ gsumsq3) {
  __shared__ __align__(16) float ss[CH];
  __shared__ __align__(16) float tt[CH];
  if (threadIdx.x < CH) {
    const float inv = 1.0f / (float)NN_TOT;
    float mu = gsum3[threadIdx.x] * inv;
    float var = gsumsq3[threadIdx.x] * inv - mu * mu;
    float s_ = g3[threadIdx.x] * rsqrtf(var + EPSV);
    ss[threadIdx.x] = s_;
    tt[threadIdx.x] = b3[threadIdx.x] - mu * s_;
  }
  __syncthreads();
  const int total = NN_TOT * CH / 4;  // f32x4 chunks
  for (int idx = blockIdx.x * blockDim.x + threadIdx.x; idx < total;
       idx += gridDim.x * blockDim.x) {
    f32x4 v = *(f32x4*)(out + (size_t)idx * 4);
    const int c0 = (idx & 31) * 4;
    f32x4 s = *(const f32x4*)(ss + c0);
    f32x4 t = *(const f32x4*)(tt + c0);
    v = s * v + t;
    *(f32x4*)(out + (size_t)idx * 4) = v;
  }
}

extern "C" void kernel_launch(void* const* d_in, const int* in_sizes, int n_in,
                              void* d_out, int out_size, void* d_ws, size_t ws_size,
                              hipStream_t stream) {
  (void)in_sizes; (void)n_in; (void)out_size; (void)ws_size;
  const float* x     = (const float*)d_in[0];
  const float* adj   = (const float*)d_in[1];
  const float* W     = (const float*)d_in[2];
  const float* bvec  = (const float*)d_in[3];
  const float* gamma = (const float*)d_in[4];
  const float* beta  = (const float*)d_in[5];

  float* R = (float*)d_out;   // fp32 activations live in d_out (16.8 MB)

  char* ws = (char*)d_ws;
  unsigned short* adjb = (unsigned short*)(ws);                   // bf16, 134 MB
  unsigned short* Yt   = (unsigned short*)(ws + 134217728);       // bf16, 8 MB
  unsigned short* Wt4  = (unsigned short*)(ws + 142606336);       // bf16, 4x32 KB
  float* gsum   = (float*)(ws + 142606336 + 131072);              // 4 x 128 f32
  float* gsumsq = (float*)(ws + 142606336 + 131072 + 2048);       // 4 x 128 f32

  init_kernel<<<4, 256, 0, stream>>>(W, Wt4, gsum, gsumsq);

  for (int i = 0; i < NLAYER; ++i) {
    if (i == 0) {
      gemm1_kernel<1><<<512, 256, 0, stream>>>(
          x, Wt4, nullptr, nullptr, nullptr, nullptr, Yt);
      gemm2_kernel<1><<<512, 256, 0, stream>>>(
          adj, nullptr, adjb, Yt, bvec, R, gsum, gsumsq);
    } else {
      gemm1_kernel<0><<<512, 256, 0, stream>>>(
          R, Wt4 + (size_t)i * CH * CH,
          gamma + (size_t)(i - 1) * CH, beta + (size_t)(i - 1) * CH,
          gsum + (size_t)(i - 1) * CH, gsumsq + (size_t)(i - 1) * CH, Yt);
      gemm2_kernel<0><<<512, 256, 0, stream>>>(
          nullptr, adjb, nullptr, Yt, bvec + (size_t)i * CH, R,
          gsum + (size_t)i * CH, gsumsq + (size_t)i * CH);
    }
  }
  out_kernel<<<512, 256, 0, stream>>>(R, gamma + 3 * CH, beta + 3 * CH,
                                      gsum + 3 * CH, gsumsq + 3 * CH);
}

// Round 5
// 587.858 us; speedup vs baseline: 1.1636x; 1.1636x over previous
//
#include <hip/hip_runtime.h>
#include <stdint.h>
#include <stddef.h>

#define BATCH 16
#define NROW 2048
#define CH 128
#define NLAYER 4
#define NN_TOT (BATCH * NROW)
#define EPSV 1e-5f
#define KS 64

typedef short short8 __attribute__((ext_vector_type(8)));
typedef float f32x4 __attribute__((ext_vector_type(4)));

static __device__ __forceinline__ unsigned short f2bf(float f) {
  union { float f; unsigned int i; } v;
  v.f = f;
  unsigned int u = v.i;
  return (unsigned short)((u + 0x7FFFu + ((u >> 16) & 1u)) >> 16);
}

// ---- init: Wt4[l][o][c] = bf16(W[l][c][o]) for all layers; zero stat slots --
__global__ void init_kernel(const float* __restrict__ W,
                            unsigned short* __restrict__ Wt4,
                            float* __restrict__ gsum, float* __restrict__ gsumsq) {
  const int l = blockIdx.x;   // 5 blocks (4 transpose + 1 zero)
  const int t = threadIdx.x;  // 256 threads
  if (l < NLAYER) {
    const float* Wl = W + (size_t)l * CH * CH;
    unsigned short* Wo = Wt4 + (size_t)l * CH * CH;
    for (int idx = t; idx < CH * CH; idx += 256) {
      int o = idx >> 7, c = idx & 127;
      Wo[idx] = f2bf(Wl[c * CH + o]);
    }
  } else {
    for (int i = t; i < NLAYER * CH; i += 256) { gsum[i] = 0.0f; gsumsq[i] = 0.0f; }
  }
}

// ---- K1: Yt[b][o][m] = (BN_affine(X) @ W)[m][o] ----------------------------
// FIRST=1: no affine (layer 0). Otherwise s,t computed in-block from stats.
template <int FIRST>
__global__ __launch_bounds__(256) void gemm1_kernel(
    const float* __restrict__ X,             // fp32 [B*N][C]
    const unsigned short* __restrict__ Wt,   // bf16 [128][128], [o][c]
    const float* __restrict__ gp, const float* __restrict__ bp,  // gamma/beta prev
    const float* __restrict__ gsumP, const float* __restrict__ gsumsqP,
    unsigned short* __restrict__ Yt) {       // bf16 [16][128][2048]
  __shared__ unsigned short As[64 * 128];    // 16 KB, 16 swizzled 16B slots/row
  __shared__ unsigned short Bs[128 * 128];   // 32 KB
  __shared__ __align__(16) float ss[CH];
  __shared__ __align__(16) float tt[CH];
  const int tid = threadIdx.x;
  const int m0 = blockIdx.x * 64;

  if (!FIRST) {
    if (tid < CH) {
      const float inv = 1.0f / (float)NN_TOT;
      float mu = gsumP[tid] * inv;
      float var = gsumsqP[tid] * inv - mu * mu;
      float s_ = gp[tid] * rsqrtf(var + EPSV);
      ss[tid] = s_;
      tt[tid] = bp[tid] - mu * s_;
    }
    __syncthreads();
  }

#pragma unroll
  for (int j = 0; j < 4; ++j) {
    int c = tid + 256 * j;
    int r = c >> 4, slot = c & 15;
    int kc = slot ^ (r & 15);
    const float* p = X + (size_t)(m0 + r) * CH + kc * 8;
    f32x4 a = *(const f32x4*)p;
    f32x4 b = *(const f32x4*)(p + 4);
    if (!FIRST) {
      f32x4 sa = *(const f32x4*)(ss + kc * 8);
      f32x4 sb = *(const f32x4*)(ss + kc * 8 + 4);
      f32x4 ta = *(const f32x4*)(tt + kc * 8);
      f32x4 tb = *(const f32x4*)(tt + kc * 8 + 4);
      a = sa * a + ta;
      b = sb * b + tb;
    }
    short8 v;
    v[0] = (short)f2bf(a[0]); v[1] = (short)f2bf(a[1]);
    v[2] = (short)f2bf(a[2]); v[3] = (short)f2bf(a[3]);
    v[4] = (short)f2bf(b[0]); v[5] = (short)f2bf(b[1]);
    v[6] = (short)f2bf(b[2]); v[7] = (short)f2bf(b[3]);
    *(short8*)(As + c * 8) = v;
  }
#pragma unroll
  for (int j = 0; j < 8; ++j) {
    int c = tid + 256 * j;
    int r = c >> 4, slot = c & 15;
    int kc = slot ^ (r & 15);
    *(short8*)(Bs + c * 8) = *(const short8*)(Wt + (size_t)r * CH + kc * 8);
  }
  __syncthreads();

  const int l = tid & 63, w = tid >> 6;
  const int mq = (w >> 1) * 32, oq = (w & 1) * 64;
  const int lr = l & 15, lq = l >> 4;
  f32x4 acc[2][4] = {};

#pragma unroll
  for (int kt = 0; kt < 4; ++kt) {
    const int kc0 = kt * 4 + lq;
    const int slotK = kc0 ^ lr;
    short8 a[2], b[4];
#pragma unroll
    for (int mi = 0; mi < 2; ++mi)
      a[mi] = *(const short8*)(As + (mq + mi * 16 + lr) * 128 + slotK * 8);
#pragma unroll
    for (int ni = 0; ni < 4; ++ni)
      b[ni] = *(const short8*)(Bs + (oq + ni * 16 + lr) * 128 + slotK * 8);
#pragma unroll
    for (int mi = 0; mi < 2; ++mi)
#pragma unroll
      for (int ni = 0; ni < 4; ++ni)
        acc[mi][ni] = __builtin_amdgcn_mfma_f32_16x16x32_bf16(a[mi], b[ni], acc[mi][ni], 0, 0, 0);
  }

  const int bat = m0 >> 11;
  const int mb = m0 & 2047;
  unsigned short* YtB = Yt + (size_t)bat * CH * NROW;
#pragma unroll
  for (int ni = 0; ni < 4; ++ni) {
    const int o = oq + ni * 16 + lr;
    unsigned short* row = YtB + (size_t)o * NROW;
#pragma unroll
    for (int mi = 0; mi < 2; ++mi) {
      const int m = mb + mq + mi * 16 + lq * 4;
      f32x4 v = acc[mi][ni];
      unsigned short p0 = f2bf(v[0]), p1 = f2bf(v[1]);
      unsigned short p2 = f2bf(v[2]), p3 = f2bf(v[3]);
      unsigned long long packed = (unsigned long long)p0 | ((unsigned long long)p1 << 16) |
                                  ((unsigned long long)p2 << 32) | ((unsigned long long)p3 << 48);
      *(unsigned long long*)(row + m) = packed;
    }
  }
}

// ---- K2: R[b][n][c] = ReLU(adj_b @ Y_b + bias)[n][c] fp32, + channel stats -
// Round-1 proven structure: A AND B staged through double-buffered LDS, one
// raw barrier per K-slab (lgkm only; counted vmcnt keeps prefetch in flight),
// 2-deep register prefetch. CVT=1 (layer 0): B from fp32 adj, converted in
// regs, bf16 copy emitted to adjO.
struct Pf {
  short8 a0, a1, a2, a3;      // A slab (Yt rows)
  short8 b0, b1;              // B slab bf16 (layers 1-3)
  f32x4 f0, f1, f2, f3;       // B slab fp32 (layer 0)
};

template <int CVT>
__global__ __launch_bounds__(256) void gemm2_kernel(
    const float* __restrict__ adjF,           // fp32 [16][2048][2048] (CVT)
    const unsigned short* __restrict__ adjH,  // bf16 [16][2048][2048] (!CVT)
    unsigned short* __restrict__ adjO,        // bf16 out (CVT)
    const unsigned short* __restrict__ Yt,    // bf16 [16][128][2048]
    const float* __restrict__ bias,           // fp32 [128]
    float* __restrict__ R,                    // fp32 [32768][128]  (== d_out)
    float* __restrict__ gsumL, float* __restrict__ gsumsqL) {
  __shared__ unsigned short As[2][CH * KS];   // 2 x 16 KB
  __shared__ unsigned short Bs[2][64 * KS];   // 2 x 8 KB
  __shared__ float redS[2][CH];
  __shared__ float redQ[2][CH];

  const int tid = threadIdx.x;
  const int bat = blockIdx.x >> 5;
  const int n0 = (blockIdx.x & 31) * 64;
  const unsigned short* YtB = Yt + (size_t)bat * CH * NROW;

  // staging: slot s8 = tid&7 (8 x 16B per 64-elem row), row r8 = tid>>3.
  const int s8 = tid & 7;
  const int r8 = tid >> 3;
  const int swz8 = (s8 ^ (r8 & 7)) * 8;

  const unsigned short* gA0 = YtB + (size_t)r8 * NROW + s8 * 8;
  const unsigned short* gA1 = gA0 + (size_t)32 * NROW;
  const unsigned short* gA2 = gA0 + (size_t)64 * NROW;
  const unsigned short* gA3 = gA0 + (size_t)96 * NROW;
  const int lA0 = r8 * KS + swz8;
  const int lA1 = lA0 + 32 * KS;
  const int lA2 = lA0 + 64 * KS;
  const int lA3 = lA0 + 96 * KS;

  const size_t bO0 = (size_t)bat * NROW * NROW + (size_t)(n0 + r8) * NROW + s8 * 8;
  const size_t bO1 = bO0 + (size_t)32 * NROW;
  const int lB0 = r8 * KS + swz8;
  const int lB1 = lB0 + 32 * KS;

  const int l = tid & 63, w = tid >> 6;
  const int cq = (w >> 1) * 64;   // channel quadrant (A rows / D rows)
  const int nh = (w & 1) * 32;    // n half (B rows / D cols)
  const int lr = l & 15, lq = l >> 4;
  const int rsw = lr & 7;

  f32x4 acc[4][2] = {};           // [c-tile][n-tile]

  auto LOADS = [&](Pf& p, int kt) {
    const int k0 = kt * KS;
    p.a0 = *(const short8*)(gA0 + k0);
    p.a1 = *(const short8*)(gA1 + k0);
    p.a2 = *(const short8*)(gA2 + k0);
    p.a3 = *(const short8*)(gA3 + k0);
    if constexpr (CVT) {
      const float* q0 = adjF + bO0 + k0;
      const float* q1 = adjF + bO1 + k0;
      p.f0 = *(const f32x4*)q0; p.f1 = *(const f32x4*)(q0 + 4);
      p.f2 = *(const f32x4*)q1; p.f3 = *(const f32x4*)(q1 + 4);
    } else {
      p.b0 = *(const short8*)(adjH + bO0 + k0);
      p.b1 = *(const short8*)(adjH + bO1 + k0);
    }
  };

  auto WRITES = [&](Pf& p, int buf, int kt) {
    unsigned short* Ap = As[buf];
    *(short8*)(Ap + lA0) = p.a0;
    *(short8*)(Ap + lA1) = p.a1;
    *(short8*)(Ap + lA2) = p.a2;
    *(short8*)(Ap + lA3) = p.a3;
    unsigned short* Bp = Bs[buf];
    if constexpr (CVT) {
      short8 q0, q1;
      q0[0] = (short)f2bf(p.f0[0]); q0[1] = (short)f2bf(p.f0[1]);
      q0[2] = (short)f2bf(p.f0[2]); q0[3] = (short)f2bf(p.f0[3]);
      q0[4] = (short)f2bf(p.f1[0]); q0[5] = (short)f2bf(p.f1[1]);
      q0[6] = (short)f2bf(p.f1[2]); q0[7] = (short)f2bf(p.f1[3]);
      q1[0] = (short)f2bf(p.f2[0]); q1[1] = (short)f2bf(p.f2[1]);
      q1[2] = (short)f2bf(p.f2[2]); q1[3] = (short)f2bf(p.f2[3]);
      q1[4] = (short)f2bf(p.f3[0]); q1[5] = (short)f2bf(p.f3[1]);
      q1[6] = (short)f2bf(p.f3[2]); q1[7] = (short)f2bf(p.f3[3]);
      *(short8*)(Bp + lB0) = q0;
      *(short8*)(Bp + lB1) = q1;
      const int k0 = kt * KS;
      *(short8*)(adjO + bO0 + k0) = q0;   // emit bf16 adj copy for layers 1-3
      *(short8*)(adjO + bO1 + k0) = q1;
    } else {
      *(short8*)(Bp + lB0) = p.b0;
      *(short8*)(Bp + lB1) = p.b1;
    }
  };

  auto COMPUTE = [&](int buf) {
    const unsigned short* Ap = As[buf];
    const unsigned short* Bp = Bs[buf];
#pragma unroll
    for (int ks = 0; ks < 2; ++ks) {
      const int sl = ((ks * 4 + lq) ^ rsw) * 8;
      short8 a0 = *(const short8*)(Ap + (cq +  0 + lr) * KS + sl);
      short8 a1 = *(const short8*)(Ap + (cq + 16 + lr) * KS + sl);
      short8 a2 = *(const short8*)(Ap + (cq + 32 + lr) * KS + sl);
      short8 a3 = *(const short8*)(Ap + (cq + 48 + lr) * KS + sl);
      short8 b0 = *(const short8*)(Bp + (nh +  0 + lr) * KS + sl);
      short8 b1 = *(const short8*)(Bp + (nh + 16 + lr) * KS + sl);
      acc[0][0] = __builtin_amdgcn_mfma_f32_16x16x32_bf16(a0, b0, acc[0][0], 0, 0, 0);
      acc[0][1] = __builtin_amdgcn_mfma_f32_16x16x32_bf16(a0, b1, acc[0][1], 0, 0, 0);
      acc[1][0] = __builtin_amdgcn_mfma_f32_16x16x32_bf16(a1, b0, acc[1][0], 0, 0, 0);
      acc[1][1] = __builtin_amdgcn_mfma_f32_16x16x32_bf16(a1, b1, acc[1][1], 0, 0, 0);
      acc[2][0] = __builtin_amdgcn_mfma_f32_16x16x32_bf16(a2, b0, acc[2][0], 0, 0, 0);
      acc[2][1] = __builtin_amdgcn_mfma_f32_16x16x32_bf16(a2, b1, acc[2][1], 0, 0, 0);
      acc[3][0] = __builtin_amdgcn_mfma_f32_16x16x32_bf16(a3, b0, acc[3][0], 0, 0, 0);
      acc[3][1] = __builtin_amdgcn_mfma_f32_16x16x32_bf16(a3, b1, acc[3][1], 0, 0, 0);
    }
  };

#define BAR() do { asm volatile("s_waitcnt lgkmcnt(0)"); __builtin_amdgcn_s_barrier(); } while (0)

  Pf s0, s1;
  // prologue: stage slab 0 via s0, then launch slab 1 (s0) and slab 2 (s1)
  LOADS(s0, 0);
  WRITES(s0, 0, 0);      // compiler inserts counted vmcnt for s0's loads
  LOADS(s0, 1);
  LOADS(s1, 2);
  BAR();                 // lgkm drained; prefetch loads stay IN FLIGHT

#pragma unroll 1
  for (int kt2 = 0; kt2 < 14; ++kt2) {
    const int kt = kt2 * 2;
    COMPUTE(0);
    WRITES(s0, 1, kt + 1);
    LOADS(s0, kt + 3);
    BAR();
    COMPUTE(1);
    WRITES(s1, 0, kt + 2);
    LOADS(s1, kt + 4);
    BAR();
  }
  // tail: slabs 28..31
  COMPUTE(0);
  WRITES(s0, 1, 29);
  LOADS(s0, 31);
  BAR();
  COMPUTE(1);
  WRITES(s1, 0, 30);
  BAR();
  COMPUTE(0);
  WRITES(s0, 1, 31);
  BAR();
  COMPUTE(1);
#undef BAR

  // epilogue: bias + relu + fp32 store + channel stats
  float* RB = R + (size_t)bat * NROW * CH;
  f32x4 sumv[4] = {};
  f32x4 sumq[4] = {};
#pragma unroll
  for (int mi = 0; mi < 4; ++mi) {
    const int c0 = cq + mi * 16 + lq * 4;
    f32x4 bia = *(const f32x4*)(bias + c0);
#pragma unroll
    for (int ni = 0; ni < 2; ++ni) {
      const int n = n0 + nh + ni * 16 + lr;
      f32x4 v = acc[mi][ni] + bia;
      v[0] = fmaxf(v[0], 0.0f);
      v[1] = fmaxf(v[1], 0.0f);
      v[2] = fmaxf(v[2], 0.0f);
      v[3] = fmaxf(v[3], 0.0f);
      sumv[mi] += v;
      sumq[mi] += v * v;
      *(f32x4*)(RB + (size_t)n * CH + c0) = v;
    }
  }
#pragma unroll
  for (int mi = 0; mi < 4; ++mi) {
#pragma unroll
    for (int d = 1; d < 16; d <<= 1) {
      sumv[mi][0] += __shfl_xor(sumv[mi][0], d);
      sumv[mi][1] += __shfl_xor(sumv[mi][1], d);
      sumv[mi][2] += __shfl_xor(sumv[mi][2], d);
      sumv[mi][3] += __shfl_xor(sumv[mi][3], d);
      sumq[mi][0] += __shfl_xor(sumq[mi][0], d);
      sumq[mi][1] += __shfl_xor(sumq[mi][1], d);
      sumq[mi][2] += __shfl_xor(sumq[mi][2], d);
      sumq[mi][3] += __shfl_xor(sumq[mi][3], d);
    }
  }
  const int nqi = w & 1;
  if (lr == 0) {
#pragma unroll
    for (int mi = 0; mi < 4; ++mi) {
      const int c0 = cq + mi * 16 + lq * 4;
      redS[nqi][c0 + 0] = sumv[mi][0];
      redS[nqi][c0 + 1] = sumv[mi][1];
      redS[nqi][c0 + 2] = sumv[mi][2];
      redS[nqi][c0 + 3] = sumv[mi][3];
      redQ[nqi][c0 + 0] = sumq[mi][0];
      redQ[nqi][c0 + 1] = sumq[mi][1];
      redQ[nqi][c0 + 2] = sumq[mi][2];
      redQ[nqi][c0 + 3] = sumq[mi][3];
    }
  }
  __syncthreads();
  if (tid < CH) {
    atomicAdd(gsumL + tid, redS[0][tid] + redS[1][tid]);
  } else {
    const int c = tid - CH;
    atomicAdd(gsumsqL + c, redQ[0][c] + redQ[1][c]);
  }
}

// ---- final BN applied in place on d_out (fp32), s/t computed in-block ------
__global__ __launch_bounds__(256) void out_kernel(
    float* __restrict__ out,
    const float* __restrict__ g3, const float* __restrict__ b3,
    const float* __restrict__ gsum3, const float* __restrict__ gsumsq3) {
  __shared__ __align__(16) float ss[CH];
  __shared__ __align__(16) float tt[CH];
  if (threadIdx.x < CH) {
    const float inv = 1.0f / (float)NN_TOT;
    float mu = gsum3[threadIdx.x] * inv;
    float var = gsumsq3[threadIdx.x] * inv - mu * mu;
    float s_ = g3[threadIdx.x] * rsqrtf(var + EPSV);
    ss[threadIdx.x] = s_;
    tt[threadIdx.x] = b3[threadIdx.x] - mu * s_;
  }
  __syncthreads();
  const int total = NN_TOT * CH / 4;  // f32x4 chunks
  for (int idx = blockIdx.x * blockDim.x + threadIdx.x; idx < total;
       idx += gridDim.x * blockDim.x) {
    f32x4 v = *(f32x4*)(out + (size_t)idx * 4);
    const int c0 = (idx & 31) * 4;
    f32x4 s = *(const f32x4*)(ss + c0);
    f32x4 t = *(const f32x4*)(tt + c0);
    v = s * v + t;
    *(f32x4*)(out + (size_t)idx * 4) = v;
  }
}

extern "C" void kernel_launch(void* const* d_in, const int* in_sizes, int n_in,
                              void* d_out, int out_size, void* d_ws, size_t ws_size,
                              hipStream_t stream) {
  (void)in_sizes; (void)n_in; (void)out_size; (void)ws_size;
  const float* x     = (const float*)d_in[0];
  const float* adj   = (const float*)d_in[1];
  const float* W     = (const float*)d_in[2];
  const float* bvec  = (const float*)d_in[3];
  const float* gamma = (const float*)d_in[4];
  const float* beta  = (const float*)d_in[5];

  float* R = (float*)d_out;   // fp32 activations live in d_out (16.8 MB)

  char* ws = (char*)d_ws;
  unsigned short* adjb = (unsigned short*)(ws);                   // bf16, 134 MB
  unsigned short* Yt   = (unsigned short*)(ws + 134217728);       // bf16, 8 MB
  unsigned short* Wt4  = (unsigned short*)(ws + 142606336);       // bf16, 4x32 KB
  float* gsum   = (float*)(ws + 142606336 + 131072);              // 4 x 128 f32
  float* gsumsq = (float*)(ws + 142606336 + 131072 + 2048);       // 4 x 128 f32

  init_kernel<<<NLAYER + 1, 256, 0, stream>>>(W, Wt4, gsum, gsumsq);

  for (int i = 0; i < NLAYER; ++i) {
    if (i == 0) {
      gemm1_kernel<1><<<512, 256, 0, stream>>>(
          x, Wt4, nullptr, nullptr, nullptr, nullptr, Yt);
      gemm2_kernel<1><<<512, 256, 0, stream>>>(
          adj, nullptr, adjb, Yt, bvec, R, gsum, gsumsq);
    } else {
      gemm1_kernel<0><<<512, 256, 0, stream>>>(
          R, Wt4 + (size_t)i * CH * CH,
          gamma + (size_t)(i - 1) * CH, beta + (size_t)(i - 1) * CH,
          gsum + (size_t)(i - 1) * CH, gsumsq + (size_t)(i - 1) * CH, Yt);
      gemm2_kernel<0><<<512, 256, 0, stream>>>(
          nullptr, adjb, nullptr, Yt, bvec + (size_t)i * CH, R,
          gsum + (size_t)i * CH, gsumsq + (size_t)i * CH);
    }
  }
  out_kernel<<<512, 256, 0, stream>>>(R, gamma + 3 * CH, beta + 3 * CH,
                                      gsum + 3 * CH, gsumsq + 3 * CH);
}